// Round 10
// baseline (504.854 us; speedup 1.0000x reference)
//
#include <hip/hip_runtime.h>
#include <hip/hip_bf16.h>

// ---------- types ----------
typedef __attribute__((ext_vector_type(8))) short short8;   // 8 bf16 (4 VGPR)
typedef __attribute__((ext_vector_type(4))) float f32x4;

#define D_IN   2048
#define D_OUT  1024

__device__ __forceinline__ short f2bf(float x) {
    union { __hip_bfloat16 h; short s; } u;
    u.h = __float2bfloat16(x);
    return u.s;
}
// fast RNE f32->bf16 (finite inputs; exact round-to-nearest-even)
__device__ __forceinline__ short f2bf_fast(float x) {
    unsigned u = __float_as_uint(x);
    u += 0x7fffu + ((u >> 16) & 1u);
    return (short)(u >> 16);
}

// ---------- 1. W [2048][1024] f32 -> Bt [1024][2048] bf16 ----------
__global__ void transpose_w_kernel(const float* __restrict__ W,
                                   short* __restrict__ Bt) {
    __shared__ float tile[32][33];
    int c0 = blockIdx.x * 32;
    int r0 = blockIdx.y * 32;
    int tc = threadIdx.x & 31;
    int tr = threadIdx.x >> 5;
#pragma unroll
    for (int i = 0; i < 32; i += 8)
        tile[tr + i][tc] = W[(long)(r0 + tr + i) * D_OUT + c0 + tc];
    __syncthreads();
#pragma unroll
    for (int i = 0; i < 32; i += 8)
        Bt[(long)(c0 + tr + i) * D_IN + r0 + tc] = f2bf(tile[tc][tr + i]);
}

// ---------- 2. Fully-fused: GEMM(64x1024x2048) + bias + ReLU + LN + pack ----------
// One block = one image, 8 waves; wave w owns cols [w*128, +128). BK=32.
// ZERO barriers / ZERO LDS in the main loop:
//  - A frags loaded per-lane direct from img (f32) and converted in-register
//    (8 waves share the same 8KB A-chunk per tile -> L1 serves re-reads).
//  - B frags direct Bt->VGPR (L2/L3-resident), one-tile ping-pong bA/bB.
// Waves drift independently; per-wave waits overlap other waves' MFMA
// (m114 wave-level co-schedule) -- no CU-wide stall points.

__global__ __launch_bounds__(512, 2)
void fused_kernel(const float* __restrict__ img, const short* __restrict__ Bt,
                  const float* __restrict__ bias, const int* __restrict__ mask,
                  const float* __restrict__ lnw, const float* __restrict__ lnb,
                  float* __restrict__ out) {
    __shared__ char LDS[8192];     // epilogue scratch only (4.6 KiB used)

    const int b    = blockIdx.x;
    const int tid  = threadIdx.x;
    const int lane = tid & 63;
    const int w    = tid >> 6;
    const int lrow = lane & 15;
    const int lchk = lane >> 4;    // k-chunk 0..3

    // A per-lane base: row b*64+lrow, k-elems lchk*8.. ; mi adds 16 rows.
    const float* pa = img + ((long)(b * 64 + lrow)) * D_IN + lchk * 8;
    // B per-lane base: col w*128 + nf*16 + lrow, 16B at k = kt*32 + lchk*8
    const short* bsrc = Bt + (long)(w * 128 + lrow) * D_IN + lchk * 8;

    f32x4 acc[4][8];
#pragma unroll
    for (int i = 0; i < 4; ++i)
#pragma unroll
        for (int j = 0; j < 8; ++j) acc[i][j] = (f32x4)0.0f;

    float4 sA[4];          // f32 staging for two mi rows-groups (reused)
    short8 fa[4];          // A frags for the 4 mi of the current tile
    short8 bA[8], bB[8];   // B frag ping-pong

#define A_LOAD01(kf) do {                                                       \
    sA[0] = *(const float4*)(pa + (kf));                                        \
    sA[1] = *(const float4*)(pa + (kf) + 4);                                    \
    sA[2] = *(const float4*)(pa + 16 * D_IN + (kf));                            \
    sA[3] = *(const float4*)(pa + 16 * D_IN + (kf) + 4);                        \
} while (0)
#define A_LOAD23(kf) do {                                                       \
    sA[0] = *(const float4*)(pa + 32 * D_IN + (kf));                            \
    sA[1] = *(const float4*)(pa + 32 * D_IN + (kf) + 4);                        \
    sA[2] = *(const float4*)(pa + 48 * D_IN + (kf));                            \
    sA[3] = *(const float4*)(pa + 48 * D_IN + (kf) + 4);                        \
} while (0)
#define CVT2(d0, d1) do {                                                       \
    const float* f_ = (const float*)sA;                                         \
    short8 c0_, c1_;                                                            \
    _Pragma("unroll") for (int i_ = 0; i_ < 4; ++i_) {                          \
        c0_[i_]     = f2bf_fast(f_[i_]);                                        \
        c0_[4 + i_] = f2bf_fast(f_[4 + i_]);                                    \
        c1_[i_]     = f2bf_fast(f_[8 + i_]);                                    \
        c1_[4 + i_] = f2bf_fast(f_[12 + i_]);                                   \
    }                                                                           \
    d0 = c0_; d1 = c1_;                                                         \
} while (0)
#define B_LOAD(dst, kt) do {                                                    \
    _Pragma("unroll") for (int nf = 0; nf < 8; ++nf)                            \
        dst[nf] = *(const short8*)(bsrc + (long)nf * 16 * D_IN + (kt) * 32);    \
} while (0)
#define MFMA_PAIR(h, fb) do {                                                   \
    __builtin_amdgcn_s_setprio(1);                                              \
    _Pragma("unroll") for (int m_ = 0; m_ < 2; ++m_)                            \
    _Pragma("unroll") for (int nf = 0; nf < 8; ++nf)                            \
        acc[(h) * 2 + m_][nf] = __builtin_amdgcn_mfma_f32_16x16x32_bf16(        \
            fa[(h) * 2 + m_], fb[nf], acc[(h) * 2 + m_][nf], 0, 0, 0);          \
    __builtin_amdgcn_s_setprio(0);                                              \
} while (0)

    // ---- prologue: tile-0 A(mi0,1) + B in flight
    A_LOAD01(0);
    B_LOAD(bA, 0);

#pragma unroll 1
    for (int t = 0; t < 64; t += 2) {
        // ---- tile t (B = bA) ----
        CVT2(fa[0], fa[1]);                 // waits sA(mi0,1) of t
        A_LOAD23(t * 32);                   // reuse sA (WAR: safe, in-order issue)
        MFMA_PAIR(0, bA);
        CVT2(fa[2], fa[3]);                 // waits sA(mi2,3)
        A_LOAD01((t + 1) * 32);             // next tile mi0,1
        B_LOAD(bB, t + 1);
        MFMA_PAIR(1, bA);
        // ---- tile t+1 (B = bB) ----
        CVT2(fa[0], fa[1]);
        A_LOAD23((t + 1) * 32);
        MFMA_PAIR(0, bB);
        CVT2(fa[2], fa[3]);
        A_LOAD01(((t + 2) & 63) * 32);      // junk at t=62, never consumed
        B_LOAD(bA, (t + 2) & 63);           // junk at t=62, never consumed
        MFMA_PAIR(1, bB);
    }

    // ---- epilogue: bias+ReLU, LN stats, mask-pack, store (R6/R7/R9-verified)
    __syncthreads();

    float* redS = (float*)LDS;             // [8][64]
    float* redQ = (float*)(LDS + 2048);    // [8][64]
    float* muT  = (float*)(LDS + 4096);    // [64]
    float* rsT  = (float*)(LDS + 4352);    // [64]

    float bb[8];
#pragma unroll
    for (int nf = 0; nf < 8; ++nf) bb[nf] = bias[w * 128 + nf * 16 + lrow];

    float s[4][4], q[4][4];
#pragma unroll
    for (int mi = 0; mi < 4; ++mi)
#pragma unroll
        for (int r = 0; r < 4; ++r) { s[mi][r] = 0.f; q[mi][r] = 0.f; }
#pragma unroll
    for (int mi = 0; mi < 4; ++mi)
#pragma unroll
        for (int nf = 0; nf < 8; ++nf)
#pragma unroll
            for (int r = 0; r < 4; ++r) {
                float v = fmaxf(acc[mi][nf][r] + bb[nf], 0.f);
                acc[mi][nf][r] = v;
                s[mi][r] += v;
                q[mi][r] += v * v;
            }
#pragma unroll
    for (int mi = 0; mi < 4; ++mi)
#pragma unroll
        for (int r = 0; r < 4; ++r)
#pragma unroll
            for (int off = 1; off <= 8; off <<= 1) {
                s[mi][r] += __shfl_xor(s[mi][r], off);
                q[mi][r] += __shfl_xor(q[mi][r], off);
            }
    if (lrow == 0) {
#pragma unroll
        for (int mi = 0; mi < 4; ++mi)
#pragma unroll
            for (int r = 0; r < 4; ++r) {
                int m = mi * 16 + lchk * 4 + r;
                redS[w * 64 + m] = s[mi][r];
                redQ[w * 64 + m] = q[mi][r];
            }
    }
    __syncthreads();
    if (tid < 64) {
        float S = 0.f, Q = 0.f;
#pragma unroll
        for (int ww = 0; ww < 8; ++ww) { S += redS[ww * 64 + tid]; Q += redQ[ww * 64 + tid]; }
        float mu  = S * (1.0f / 1024.0f);
        float var = Q * (1.0f / 1024.0f) - mu * mu;
        muT[tid] = mu;
        rsT[tid] = rsqrtf(var + 1e-12f);
    }
    __syncthreads();

    int mv = mask[(b << 6) | lane];
    unsigned long long bal = __ballot(mv != 0);
    int cnt = __popcll(bal);

    float lw[8], lb[8];
#pragma unroll
    for (int nf = 0; nf < 8; ++nf) {
        int col = w * 128 + nf * 16 + lrow;
        lw[nf] = lnw[col];
        lb[nf] = lnb[col];
    }
#pragma unroll
    for (int mi = 0; mi < 4; ++mi)
#pragma unroll
        for (int r = 0; r < 4; ++r) {
            int m = mi * 16 + lchk * 4 + r;
            if ((bal >> m) & 1ull) {
                int d = __popcll(bal & ((1ull << m) - 1ull));
                float mu = muT[m], rs = rsT[m];
                long obase = ((long)(b << 6) + d) * D_OUT + w * 128 + lrow;
#pragma unroll
                for (int nf = 0; nf < 8; ++nf)
                    out[obase + nf * 16] = (acc[mi][nf][r] - mu) * rs * lw[nf] + lb[nf];
            }
        }
    // zero the padded tail rows (deterministic full coverage of d_out)
    for (int d = cnt; d < 64; ++d) {
        float2 z = make_float2(0.f, 0.f);
        *(float2*)(out + ((long)(b << 6) + d) * D_OUT + w * 128 + lane * 2) = z;
    }
}

// ---------- launch ----------
extern "C" void kernel_launch(void* const* d_in, const int* in_sizes, int n_in,
                              void* d_out, int out_size, void* d_ws, size_t ws_size,
                              hipStream_t stream) {
    const float* img  = (const float*)d_in[0];
    const int*   mask = (const int*)d_in[2];
    const float* W    = (const float*)d_in[4];
    const float* bias = (const float*)d_in[5];
    const float* lnw  = (const float*)d_in[6];
    const float* lnb  = (const float*)d_in[7];
    float* out = (float*)d_out;

    short* Bt = (short*)d_ws;   // 4 MiB

    transpose_w_kernel<<<dim3(D_OUT / 32, D_IN / 32), 256, 0, stream>>>(W, Bt);
    fused_kernel<<<512, 512, 0, stream>>>(img, Bt, bias, mask, lnw, lnb, out);
}

// Round 11
// 317.523 us; speedup vs baseline: 1.5900x; 1.5900x over previous
//
#include <hip/hip_runtime.h>
#include <hip/hip_bf16.h>

// ---------- types ----------
typedef __attribute__((ext_vector_type(8))) short short8;   // 8 bf16 (4 VGPR)
typedef __attribute__((ext_vector_type(4))) short short4v;  // 4 bf16
typedef __attribute__((ext_vector_type(4))) float f32x4;

#define D_IN   2048
#define D_OUT  1024
#define M_ROWS 32768

__device__ __forceinline__ short f2bf(float x) {
    union { __hip_bfloat16 h; short s; } u;
    u.h = __float2bfloat16(x);
    return u.s;
}
__device__ __forceinline__ float bf2f(short s) {
    union { short s; __hip_bfloat16 h; } u;
    u.s = s;
    return __bfloat162float(u.h);
}

// ---------- 1. W [2048][1024] f32 -> Bt [1024][2048] bf16 ----------
__global__ void transpose_w_kernel(const float* __restrict__ W,
                                   short* __restrict__ Bt) {
    __shared__ float tile[32][33];
    int c0 = blockIdx.x * 32;
    int r0 = blockIdx.y * 32;
    int tc = threadIdx.x & 31;
    int tr = threadIdx.x >> 5;
#pragma unroll
    for (int i = 0; i < 32; i += 8)
        tile[tr + i][tc] = W[(long)(r0 + tr + i) * D_OUT + c0 + tc];
    __syncthreads();
#pragma unroll
    for (int i = 0; i < 32; i += 8)
        Bt[(long)(c0 + tr + i) * D_IN + r0 + tc] = f2bf(tile[tc][tr + i]);
}

// ---------- 2. GEMM 256x256 BK=64, 4-phase lookahead, A-cast FUSED ----------
// = R4 champion structure; A staged f32->reg->cvt->swizzled ds_write with
// full-ledger cover (A0 issued P1, A1 issued P2, confirmed P3/P4).
// LDS map (131072 B): A at 0 (buf p at p*32768, half h at h*16384), B at 65536.
// Swizzle both sides: phys = logical ^ ((row&7)<<4) within a 16 KB half.
#define HALF_BYTES 16384

__device__ __forceinline__ void stage_half_B(const short* __restrict__ mat, long row0, int k0,
                                             char* ldsbase, int tid) {
#pragma unroll
    for (int j = 0; j < 2; ++j) {
        int d = j * 8192 + tid * 16;            // physical (linear dest for glds)
        int s = d ^ (((d >> 7) & 7) << 4);      // logical
        int row = s >> 7;
        int ke  = (s & 127) >> 1;
        __builtin_amdgcn_global_load_lds(
            (const __attribute__((address_space(1))) void*)(mat + (row0 + row) * D_IN + k0 + ke),
            (__attribute__((address_space(3))) void*)(ldsbase + d), 16, 0, 0);
    }
}

#define BAR()    __builtin_amdgcn_s_barrier()
#define SB0()    __builtin_amdgcn_sched_barrier(0)
#define LGKM(n)  do { asm volatile("s_waitcnt lgkmcnt(" #n ")" ::: "memory"); SB0(); } while (0)
#define VMW(n)   do { asm volatile("s_waitcnt vmcnt(" #n ")" ::: "memory"); SB0(); } while (0)

__global__ __launch_bounds__(512, 2)
void gemm256_kernel(const float* __restrict__ A,   // img f32 [32768][2048]
                    const short* __restrict__ Bt,  // [1024][2048] bf16
                    const float* __restrict__ bias, short* __restrict__ H) {
    __shared__ char LDS[131072];

    // XCD-bijective swizzle (512 % 8 == 0); bn fastest within chunk.
    int bid = blockIdx.x;
    int lid = (bid & 7) * 64 + (bid >> 3);
    int bn = lid & 3;
    int bm = lid >> 2;

    int tid  = threadIdx.x;
    int lane = tid & 63;
    int wave = tid >> 6;
    int wm = wave >> 2;            // A half
    int wn = wave & 3;
    int bh = wn >> 1;              // B half
    int lrow = lane & 15;
    int lkb  = (lane >> 4) * 16;

    // per-lane swizzled fragment bases (XOR folded; +mi*2048/+8192 touch bits>=11)
    int swz = (lrow & 7) << 4;
    int la0 = (lrow * 128 + lkb) ^ swz;
    int la1 = (lrow * 128 + 64 + lkb) ^ swz;
    int aO0 = wm * HALF_BYTES + la0;
    int aO1 = wm * HALF_BYTES + la1;
    int bO0 = 65536 + bh * HALF_BYTES + (wn & 1) * 8192 + la0;
    int bO1 = 65536 + bh * HALF_BYTES + (wn & 1) * 8192 + la1;

    // per-thread A-stage coords (same mapping as stage_half_B's inverse)
    int ar_[2], ak_[2];
#pragma unroll
    for (int j = 0; j < 2; ++j) {
        int d = j * 8192 + tid * 16;
        int s = d ^ (((d >> 7) & 7) << 4);
        ar_[j] = s >> 7;
        ak_[j] = (s & 127) >> 1;
    }

    const long arow0 = (long)bm * 256;
    const long brow0 = (long)bn * 256;

    f32x4 acc[8][4];
#pragma unroll
    for (int i = 0; i < 8; ++i)
#pragma unroll
        for (int j = 0; j < 4; ++j) acc[i][j] = (f32x4)0.0f;

    const int nt = D_IN / 64;   // 32

#define RD(off) (*(const short8*)(LDS + (off)))
// A reg-stage: issue 4 float4 (f32, 8 elems x2 atoms) for one 128x64 half
#define A_ISSUE(sa, rowbase, k0) do {                                           \
    _Pragma("unroll") for (int j = 0; j < 2; ++j) {                             \
        const float* p_ = A + ((rowbase) + ar_[j]) * D_IN + (k0) + ak_[j];      \
        sa[j * 2]     = *(const float4*)p_;                                     \
        sa[j * 2 + 1] = *(const float4*)(p_ + 4);                               \
    }                                                                           \
} while (0)
// cvt + 2 swizzled ds_write_b128 into an A half at ldsoff
#define A_WRITE(sa, ldsoff) do {                                                \
    _Pragma("unroll") for (int j = 0; j < 2; ++j) {                             \
        const float* f_ = (const float*)(sa + j * 2);                           \
        short8 c_;                                                              \
        _Pragma("unroll") for (int i_ = 0; i_ < 8; ++i_) c_[i_] = f2bf(f_[i_]); \
        *(short8*)(LDS + (ldsoff) + j * 8192 + tid * 16) = c_;                  \
    }                                                                           \
} while (0)
#define MFMA16(ACC_M, BFRAG, NJ0) do {                                          \
    __builtin_amdgcn_s_setprio(1);                                              \
    _Pragma("unroll") for (int mi = 0; mi < 4; ++mi)                            \
    _Pragma("unroll") for (int nj = 0; nj < 2; ++nj)                            \
    _Pragma("unroll") for (int ks = 0; ks < 2; ++ks)                            \
        acc[(ACC_M) + mi][(NJ0) + nj] = __builtin_amdgcn_mfma_f32_16x16x32_bf16(\
            aF[ks][mi], BFRAG[ks][nj], acc[(ACC_M) + mi][(NJ0) + nj], 0, 0, 0); \
    __builtin_amdgcn_s_setprio(0);                                              \
} while (0)

    float4 sA0[4], sA1[4];
    short8 aF[2][4], bN0[2][2], bN1[2][2];

    // ---- prologue ----
    A_ISSUE(sA0, arow0,       0);                       // 4 vm
    A_ISSUE(sA1, arow0 + 128, 0);                       // 4 vm
    stage_half_B(Bt, brow0,       0, LDS + 65536,              tid);  // 2 vm
    stage_half_B(Bt, brow0 + 128, 0, LDS + 65536 + HALF_BYTES, tid);  // 2 vm
    VMW(4);                          // fA(0) done; B(0) in flight
    A_WRITE(sA0, 0);                 // A0(0) -> buf0
    A_WRITE(sA1, HALF_BYTES);        // A1(0) -> buf0
    stage_half_B(Bt, brow0,       64, LDS + 65536 + 32768,              tid);
    stage_half_B(Bt, brow0 + 128, 64, LDS + 65536 + 32768 + HALF_BYTES, tid);
    VMW(4);                          // B(0) landed; B(1) x4 in flight
    LGKM(0);                         // A writes drained
    BAR(); SB0();
    // preload tile0: bN0 then aF<-M0  (12 ds reads, confirmed at P1 LGKM(8))
#pragma unroll
    for (int j = 0; j < 2; ++j) { bN0[0][j] = RD(bO0 + j * 2048); bN0[1][j] = RD(bO1 + j * 2048); }
#pragma unroll
    for (int mi = 0; mi < 4; ++mi) { aF[0][mi] = RD(aO0 + mi * 2048); aF[1][mi] = RD(aO1 + mi * 2048); }

#pragma unroll 1
    for (int t = 0; t < nt; ++t) {
        int bufo  = (t & 1) * 32768;
        int nbufo = bufo ^ 32768;
        int k1 = ((t + 1) & (nt - 1)) * 64;
        int k2 = ((t + 2) & (nt - 1)) * 64;

        // ---- P1: read bN1(t) [8 ds]; issue A0(t+1) [4 vm]; MFMA M0N0
#pragma unroll
        for (int j = 0; j < 2; ++j) {
            bN1[0][j] = RD(bufo + bO0 + (2 + j) * 2048);
            bN1[1][j] = RD(bufo + bO1 + (2 + j) * 2048);
        }
        A_ISSUE(sA0, arow0, k1);
        LGKM(8);                     // preload bN0+aF confirmed (leaves bN1)
        MFMA16(0, bN0, 0);

        // ---- P2: issue A1(t+1) [4 vm]; glds B0(t+2) [2 vm]; MFMA M0N1
        BAR(); SB0();
        A_ISSUE(sA1, arow0 + 128, k1);
        stage_half_B(Bt, brow0, k2, LDS + 65536 + bufo, tid);
        LGKM(0);                     // bN1 confirmed
        MFMA16(0, bN1, 2);

        // ---- P3: read aF<-M1(t) [8 ds]; glds B1(t+2) [2 vm];
        //          VMW(8): B(t+1)+A0(t+1) complete; write A0(t+1); MFMA M1N0
        BAR(); SB0();
#pragma unroll
        for (int mi = 0; mi < 4; ++mi) {
            aF[0][mi] = RD(bufo + aO0 + 8192 + mi * 2048);
            aF[1][mi] = RD(bufo + aO1 + 8192 + mi * 2048);
        }
        stage_half_B(Bt, brow0 + 128, k2, LDS + 65536 + bufo + HALF_BYTES, tid);
        VMW(8);                      // [B0(t+1)2 B1(t+1)2 A0(t+1)4] done; 8 left
        A_WRITE(sA0, nbufo);         // A0(t+1) -> next buf  (+2 ds_wr)
        LGKM(2);                     // aF(M1) reads confirmed (leaves 2 writes)
        MFMA16(4, bN0, 0);

        // ---- P4: VMW(4): A1(t+1) done (B(t+2) x4 stays in flight);
        //          write A1(t+1); publish; preload bN0(t+1); MFMA M1N1; preload aF(t+1)
        VMW(4);
        A_WRITE(sA1, nbufo + HALF_BYTES);
        LGKM(0);                     // all ds_writes drained
        BAR(); SB0();                // buf(t+1) published
#pragma unroll
        for (int j = 0; j < 2; ++j) {
            bN0[0][j] = RD(nbufo + bO0 + j * 2048);
            bN0[1][j] = RD(nbufo + bO1 + j * 2048);
        }
        MFMA16(4, bN1, 2);           // uses aF(M1) — reads below are WAR-safe
#pragma unroll
        for (int mi = 0; mi < 4; ++mi) {
            aF[0][mi] = RD(nbufo + aO0 + mi * 2048);
            aF[1][mi] = RD(nbufo + aO1 + mi * 2048);
        }
    }
#undef RD

    // ---- epilogue: + bias, ReLU, store bf16.  C/D: col=lane&15, row=(lane>>4)*4+reg
    float bb[4];
#pragma unroll
    for (int nj = 0; nj < 4; ++nj)
        bb[nj] = bias[bn * 256 + wn * 64 + nj * 16 + lrow];
#pragma unroll
    for (int mi = 0; mi < 8; ++mi) {
        long row = arow0 + wm * 128 + mi * 16 + (lane >> 4) * 4;
#pragma unroll
        for (int nj = 0; nj < 4; ++nj) {
            int col = bn * 256 + wn * 64 + nj * 16 + lrow;
#pragma unroll
            for (int r = 0; r < 4; ++r) {
                float v = fmaxf(acc[mi][nj][r] + bb[nj], 0.0f);
                H[(row + r) * D_OUT + col] = f2bf(v);
            }
        }
    }
}

// ---------- 3. LayerNorm + mask-pack (dest-indexed; writes EVERY output row) ----------
__global__ void ln_pack_kernel(const short* __restrict__ H,      // bf16 [32768][1024]
                               const int* __restrict__ mask,     // [512][64]
                               const float* __restrict__ ln_w,
                               const float* __restrict__ ln_b,
                               float* __restrict__ out) {        // [512][64][1024]
    int drow = blockIdx.x;
    int b = drow >> 6, j = drow & 63;
    int tid = threadIdx.x;
    int lane = tid & 63;
    int wave = tid >> 6;
    int base = tid * 4;

    int mv = mask[(b << 6) | lane];
    unsigned long long bal = __ballot(mv != 0);
    int cnt = __popcll(bal);

    float4 o = make_float4(0.f, 0.f, 0.f, 0.f);
    if (j < cnt) {
        int pre = __popcll(bal & ((1ull << lane) - 1ull));
        unsigned long long sel = __ballot(mv != 0 && pre == j);
        int srcn = (int)__builtin_ctzll(sel);
        long row = (long)((b << 6) | srcn);

        short4v hv = *(const short4v*)(H + row * D_OUT + base);
        float v0 = bf2f(hv[0]), v1 = bf2f(hv[1]), v2 = bf2f(hv[2]), v3 = bf2f(hv[3]);

        float s  = v0 + v1 + v2 + v3;
        float s2 = v0 * v0 + v1 * v1 + v2 * v2 + v3 * v3;
#pragma unroll
        for (int off = 32; off > 0; off >>= 1) {
            s  += __shfl_xor(s, off);
            s2 += __shfl_xor(s2, off);
        }
        __shared__ float red[8];
        if (lane == 0) { red[wave] = s; red[wave + 4] = s2; }
        __syncthreads();
        float S  = red[0] + red[1] + red[2] + red[3];
        float S2 = red[4] + red[5] + red[6] + red[7];
        float mu   = S * (1.0f / D_OUT);
        float var  = S2 * (1.0f / D_OUT) - mu * mu;
        float rstd = rsqrtf(var + 1e-12f);

        float4 wv = *(const float4*)(ln_w + base);
        float4 bv = *(const float4*)(ln_b + base);
        o.x = (v0 - mu) * rstd * wv.x + bv.x;
        o.y = (v1 - mu) * rstd * wv.y + bv.y;
        o.z = (v2 - mu) * rstd * wv.z + bv.z;
        o.w = (v3 - mu) * rstd * wv.w + bv.w;
    }
    *(float4*)(out + (long)drow * D_OUT + base) = o;
}

// ---------- launch ----------
extern "C" void kernel_launch(void* const* d_in, const int* in_sizes, int n_in,
                              void* d_out, int out_size, void* d_ws, size_t ws_size,
                              hipStream_t stream) {
    const float* img  = (const float*)d_in[0];
    const int*   mask = (const int*)d_in[2];
    const float* W    = (const float*)d_in[4];
    const float* bias = (const float*)d_in[5];
    const float* lnw  = (const float*)d_in[6];
    const float* lnb  = (const float*)d_in[7];
    float* out = (float*)d_out;

    short* Bt = (short*)d_ws;                        // 4 MiB
    short* H  = (short*)d_ws + (long)D_OUT * D_IN;   // 64 MiB

    transpose_w_kernel<<<dim3(D_OUT / 32, D_IN / 32), 256, 0, stream>>>(W, Bt);
    gemm256_kernel<<<(M_ROWS / 256) * (D_OUT / 256), 512, 0, stream>>>(img, Bt, bias, H);
    ln_pack_kernel<<<M_ROWS, 256, 0, stream>>>(H, mask, lnw, lnb, out);
}